// Round 2
// baseline (437.529 us; speedup 1.0000x reference)
//
#include <hip/hip_runtime.h>
#include <stdint.h>

#define N_FEAT 32
#define NB_SHIFT 6                    // 64 nodes per bucket
#define NODES_PER_BUCKET (1 << NB_SHIFT)
#define MAX_BUCKETS 2048              // supports up to 131072 nodes
#define CURSOR_STRIDE 16              // pad cursors/hist to one 64B line each

// ---------- fallback path (baseline, known-correct) ----------
__global__ void zero_out(float* __restrict__ out, int n) {
    int i = blockIdx.x * blockDim.x + threadIdx.x;
    if (i < n) out[i] = 0.0f;
}

__global__ void mp_scatter_add(const float* __restrict__ x,
                               const int* __restrict__ src,
                               const int* __restrict__ dst,
                               float* __restrict__ out,
                               int n_edges) {
    long long tid = (long long)blockIdx.x * blockDim.x + threadIdx.x;
    long long total = (long long)n_edges * N_FEAT;
    if (tid >= total) return;
    int e = (int)(tid >> 5);
    int f = (int)(tid & 31);
    atomicAdd(&out[(long long)dst[e] * N_FEAT + f],
              x[(long long)src[e] * N_FEAT + f]);
}

// ---------- fast path: counting-sort by 64-node bucket + LDS aggregation ----------

// K1: histogram of bucket ids, pre-aggregated in LDS per block.
__global__ void hist_kernel(const int* __restrict__ dst, int n_edges,
                            int* __restrict__ histPadded, int nbuckets) {
    __shared__ int lh[MAX_BUCKETS];
    for (int j = threadIdx.x; j < nbuckets; j += blockDim.x) lh[j] = 0;
    __syncthreads();
    int stride = gridDim.x * blockDim.x;
    for (int i = blockIdx.x * blockDim.x + threadIdx.x; i < n_edges; i += stride)
        atomicAdd(&lh[dst[i] >> NB_SHIFT], 1);          // LDS atomic
    __syncthreads();
    for (int j = threadIdx.x; j < nbuckets; j += blockDim.x) {
        int c = lh[j];
        if (c) atomicAdd(&histPadded[j * CURSOR_STRIDE], c);
    }
}

// K2: single-block exclusive scan over nbuckets (chunked Hillis-Steele).
// Writes offsets[0..nbuckets] and initializes padded cursors to bucket starts.
__global__ void scan_kernel(const int* __restrict__ histPadded, int nbuckets,
                            int* __restrict__ offsets, int* __restrict__ cursorsPadded) {
    __shared__ int s[1024];
    __shared__ int carry_s;
    int tid = threadIdx.x;
    if (tid == 0) { carry_s = 0; offsets[0] = 0; }
    __syncthreads();
    for (int base = 0; base < nbuckets; base += 1024) {
        int idx = base + tid;
        int v = (idx < nbuckets) ? histPadded[idx * CURSOR_STRIDE] : 0;
        s[tid] = v;
        __syncthreads();
        // inclusive scan of s[0..1023]
        for (int off = 1; off < 1024; off <<= 1) {
            int t = 0;
            if (tid >= off) t = s[tid - off];
            __syncthreads();
            if (tid >= off) s[tid] += t;
            __syncthreads();
        }
        int carry = carry_s;
        if (idx < nbuckets) {
            int incl = carry + s[tid];
            offsets[idx + 1] = incl;                       // inclusive end
            cursorsPadded[idx * CURSOR_STRIDE] = incl - v; // exclusive start
        }
        __syncthreads();
        if (tid == 1023) carry_s = carry + s[1023];
        __syncthreads();
    }
}

// K3: scatter edges into bucket-sorted order. Pack (src, dst%64) into uint32.
__global__ void scatter_kernel(const int* __restrict__ src, const int* __restrict__ dst,
                               int n_edges, int* __restrict__ cursorsPadded,
                               uint32_t* __restrict__ sorted) {
    int i = blockIdx.x * blockDim.x + threadIdx.x;
    if (i >= n_edges) return;
    int d = dst[i];
    int b = d >> NB_SHIFT;
    int pos = atomicAdd(&cursorsPadded[b * CURSOR_STRIDE], 1);
    sorted[pos] = ((uint32_t)src[i] << NB_SHIFT) | (uint32_t)(d & (NODES_PER_BUCKET - 1));
}

// K4: one block per bucket. Gather x[src] rows, accumulate in LDS, write rows once.
__global__ void aggregate_kernel(const float* __restrict__ x,
                                 const uint32_t* __restrict__ sorted,
                                 const int* __restrict__ offsets,
                                 float* __restrict__ out, int n_nodes) {
    __shared__ float acc[NODES_PER_BUCKET * N_FEAT];   // 64*32*4 = 8 KB
    const int b = blockIdx.x;
    for (int i = threadIdx.x; i < NODES_PER_BUCKET * N_FEAT; i += blockDim.x)
        acc[i] = 0.0f;
    __syncthreads();

    const int beg = offsets[b];
    const int end = offsets[b + 1];
    const int f = threadIdx.x & (N_FEAT - 1);          // feature lane 0..31
    const int egrp = threadIdx.x >> 5;                 // 0..7 (256 threads)
    const int nerp = blockDim.x >> 5;                  // 8 edges in flight

    for (int i = beg + egrp; i < end; i += nerp) {
        uint32_t e = sorted[i];
        int src = (int)(e >> NB_SHIFT);
        int slot = (int)(e & (NODES_PER_BUCKET - 1));
        float v = x[(long long)src * N_FEAT + f];      // coalesced 128B row read
        atomicAdd(&acc[slot * N_FEAT + f], v);         // LDS atomic, bank = f
    }
    __syncthreads();

    // coalesced row writes; out[b*2048 + i] == out[node*32 + feat]
    const long long obase = (long long)b * NODES_PER_BUCKET * N_FEAT;
    const int lim = n_nodes * N_FEAT;
    for (int i = threadIdx.x; i < NODES_PER_BUCKET * N_FEAT; i += blockDim.x) {
        long long oi = obase + i;
        if (oi < lim) out[oi] = acc[i];
    }
}

extern "C" void kernel_launch(void* const* d_in, const int* in_sizes, int n_in,
                              void* d_out, int out_size, void* d_ws, size_t ws_size,
                              hipStream_t stream) {
    const float* x   = (const float*)d_in[0];
    const int*   ei  = (const int*)d_in[1];
    float*       out = (float*)d_out;

    const int n_edges = in_sizes[1] / 2;
    const int n_nodes = in_sizes[0] / N_FEAT;
    const int* src = ei;
    const int* dst = ei + n_edges;

    const int nbuckets = (n_nodes + NODES_PER_BUCKET - 1) >> NB_SHIFT;

    // workspace layout
    size_t off_sorted  = 0;
    size_t off_hist    = off_sorted + (size_t)n_edges * sizeof(uint32_t);
    size_t off_offsets = off_hist + (size_t)nbuckets * CURSOR_STRIDE * sizeof(int);
    size_t off_cursor  = off_offsets + (size_t)(nbuckets + 1) * sizeof(int);
    size_t ws_needed   = off_cursor + (size_t)nbuckets * CURSOR_STRIDE * sizeof(int);

    if (nbuckets > MAX_BUCKETS || ws_size < ws_needed) {
        // fallback: baseline atomic scatter (correct, slower)
        int threads = 256;
        zero_out<<<(out_size + threads - 1) / threads, threads, 0, stream>>>(out, out_size);
        long long total = (long long)n_edges * N_FEAT;
        mp_scatter_add<<<(int)((total + threads - 1) / threads), threads, 0, stream>>>(
            x, src, dst, out, n_edges);
        return;
    }

    char* ws = (char*)d_ws;
    uint32_t* sorted      = (uint32_t*)(ws + off_sorted);
    int*      histPadded  = (int*)(ws + off_hist);
    int*      offsets     = (int*)(ws + off_offsets);
    int*      cursors     = (int*)(ws + off_cursor);

    hipMemsetAsync(histPadded, 0, (size_t)nbuckets * CURSOR_STRIDE * sizeof(int), stream);

    hist_kernel<<<256, 256, 0, stream>>>(dst, n_edges, histPadded, nbuckets);
    scan_kernel<<<1, 1024, 0, stream>>>(histPadded, nbuckets, offsets, cursors);
    scatter_kernel<<<(n_edges + 255) / 256, 256, 0, stream>>>(src, dst, n_edges, cursors, sorted);
    aggregate_kernel<<<nbuckets, 256, 0, stream>>>(x, sorted, offsets, out, n_nodes);
}

// Round 3
// 363.573 us; speedup vs baseline: 1.2034x; 1.2034x over previous
//
#include <hip/hip_runtime.h>
#include <stdint.h>

#define N_FEAT 32
#define NB_SHIFT 6                    // 64 nodes per bucket
#define NODES_PER_BUCKET (1 << NB_SHIFT)
#define MAX_BUCKETS 2048              // supports up to 131072 nodes
#define SCATTER_BLOCKS 256

// ---------- fallback path (baseline, known-correct) ----------
__global__ void zero_out(float* __restrict__ out, int n) {
    int i = blockIdx.x * blockDim.x + threadIdx.x;
    if (i < n) out[i] = 0.0f;
}

__global__ void mp_scatter_add(const float* __restrict__ x,
                               const int* __restrict__ src,
                               const int* __restrict__ dst,
                               float* __restrict__ out,
                               int n_edges) {
    long long tid = (long long)blockIdx.x * blockDim.x + threadIdx.x;
    long long total = (long long)n_edges * N_FEAT;
    if (tid >= total) return;
    int e = (int)(tid >> 5);
    int f = (int)(tid & 31);
    atomicAdd(&out[(long long)dst[e] * N_FEAT + f],
              x[(long long)src[e] * N_FEAT + f]);
}

// ---------- fast path: counting-sort by 64-node bucket + LDS aggregation ----------

// K1: global histogram of bucket ids, pre-aggregated in LDS per block.
__global__ void hist_kernel(const int* __restrict__ dst, int n_edges,
                            int* __restrict__ hist, int nbuckets) {
    __shared__ int lh[MAX_BUCKETS];
    for (int j = threadIdx.x; j < nbuckets; j += blockDim.x) lh[j] = 0;
    __syncthreads();
    int stride = gridDim.x * blockDim.x;
    for (int i = blockIdx.x * blockDim.x + threadIdx.x; i < n_edges; i += stride)
        atomicAdd(&lh[dst[i] >> NB_SHIFT], 1);          // LDS atomic
    __syncthreads();
    for (int j = threadIdx.x; j < nbuckets; j += blockDim.x) {
        int c = lh[j];
        if (c) atomicAdd(&hist[j], c);
    }
}

// K2: single-block exclusive scan (chunked Hillis-Steele).
// offsets[0..nbuckets]; cursor[j] = exclusive start (for block reservations).
__global__ void scan_kernel(const int* __restrict__ hist, int nbuckets,
                            int* __restrict__ offsets, int* __restrict__ cursor) {
    __shared__ int s[1024];
    __shared__ int carry_s;
    int tid = threadIdx.x;
    if (tid == 0) { carry_s = 0; offsets[0] = 0; }
    __syncthreads();
    for (int base = 0; base < nbuckets; base += 1024) {
        int idx = base + tid;
        int v = (idx < nbuckets) ? hist[idx] : 0;
        s[tid] = v;
        __syncthreads();
        for (int off = 1; off < 1024; off <<= 1) {
            int t = 0;
            if (tid >= off) t = s[tid - off];
            __syncthreads();
            if (tid >= off) s[tid] += t;
            __syncthreads();
        }
        int carry = carry_s;
        if (idx < nbuckets) {
            int incl = carry + s[tid];
            offsets[idx + 1] = incl;
            cursor[idx] = incl - v;
        }
        __syncthreads();
        if (tid == 1023) carry_s = carry + s[1023];
        __syncthreads();
    }
}

// K3: hierarchical scatter. Per block: LDS hist of its chunk -> ONE global
// atomic reservation per touched bucket -> LDS-cursor scatter.
__global__ void scatter_kernel(const int* __restrict__ src, const int* __restrict__ dst,
                               int n_edges, int* __restrict__ cursor,
                               uint32_t* __restrict__ sorted, int nbuckets) {
    __shared__ int lh[MAX_BUCKETS];     // pass 1: counts; pass 2: local cursor
    __shared__ int lbase[MAX_BUCKETS];  // global base per bucket for this block
    const int chunk = (n_edges + gridDim.x - 1) / gridDim.x;
    const int beg = blockIdx.x * chunk;
    const int end = min(beg + chunk, n_edges);

    for (int j = threadIdx.x; j < nbuckets; j += blockDim.x) lh[j] = 0;
    __syncthreads();
    for (int i = beg + threadIdx.x; i < end; i += blockDim.x)
        atomicAdd(&lh[dst[i] >> NB_SHIFT], 1);
    __syncthreads();
    for (int j = threadIdx.x; j < nbuckets; j += blockDim.x) {
        int c = lh[j];
        lbase[j] = c ? atomicAdd(&cursor[j], c) : 0;   // one global atomic per (block,bucket)
        lh[j] = 0;                                     // becomes local cursor
    }
    __syncthreads();
    for (int i = beg + threadIdx.x; i < end; i += blockDim.x) {
        int d = dst[i];
        int b = d >> NB_SHIFT;
        int p = lbase[b] + atomicAdd(&lh[b], 1);       // LDS atomic
        sorted[p] = ((uint32_t)src[i] << NB_SHIFT) | (uint32_t)(d & (NODES_PER_BUCKET - 1));
    }
}

// K4: one block per bucket, ILP-8 per 32-lane edge group.
__global__ void __launch_bounds__(256)
aggregate_kernel(const float* __restrict__ x,
                 const uint32_t* __restrict__ sorted,
                 const int* __restrict__ offsets,
                 float* __restrict__ out, int n_nodes) {
    __shared__ float acc[NODES_PER_BUCKET * N_FEAT];   // 8 KB
    const int b = blockIdx.x;
    for (int i = threadIdx.x; i < NODES_PER_BUCKET * N_FEAT; i += blockDim.x)
        acc[i] = 0.0f;
    __syncthreads();

    const int beg = offsets[b];
    const int end = offsets[b + 1];
    const int f = threadIdx.x & (N_FEAT - 1);          // feature lane 0..31
    const int egrp = threadIdx.x >> 5;                 // 0..7

    int base = beg + egrp * 8;
    // fast path: 8 edges in flight per group (static indices -> registers)
    for (; base + 8 <= end; base += 64) {
        uint32_t e[8];
        float v[8];
#pragma unroll
        for (int k = 0; k < 8; ++k) e[k] = sorted[base + k];
#pragma unroll
        for (int k = 0; k < 8; ++k)
            v[k] = x[(size_t)(e[k] >> NB_SHIFT) * N_FEAT + f];   // 8 independent gathers
#pragma unroll
        for (int k = 0; k < 8; ++k)
            atomicAdd(&acc[(e[k] & (NODES_PER_BUCKET - 1)) * N_FEAT + f], v[k]); // bank=f, 2-way
    }
    // tail (< 8 edges for this group)
    {
        int stop = min(base + 8, end);
        for (int i = base; i < stop; ++i) {
            uint32_t e = sorted[i];
            float v = x[(size_t)(e >> NB_SHIFT) * N_FEAT + f];
            atomicAdd(&acc[(e & (NODES_PER_BUCKET - 1)) * N_FEAT + f], v);
        }
    }
    __syncthreads();

    const long long obase = (long long)b * NODES_PER_BUCKET * N_FEAT;
    const int lim = n_nodes * N_FEAT;
    for (int i = threadIdx.x; i < NODES_PER_BUCKET * N_FEAT; i += blockDim.x) {
        long long oi = obase + i;
        if (oi < lim) out[oi] = acc[i];
    }
}

extern "C" void kernel_launch(void* const* d_in, const int* in_sizes, int n_in,
                              void* d_out, int out_size, void* d_ws, size_t ws_size,
                              hipStream_t stream) {
    const float* x   = (const float*)d_in[0];
    const int*   ei  = (const int*)d_in[1];
    float*       out = (float*)d_out;

    const int n_edges = in_sizes[1] / 2;
    const int n_nodes = in_sizes[0] / N_FEAT;
    const int* src = ei;
    const int* dst = ei + n_edges;

    const int nbuckets = (n_nodes + NODES_PER_BUCKET - 1) >> NB_SHIFT;

    // workspace layout (unpadded)
    size_t off_sorted  = 0;
    size_t off_hist    = off_sorted + (size_t)n_edges * sizeof(uint32_t);
    size_t off_offsets = off_hist + (size_t)nbuckets * sizeof(int);
    size_t off_cursor  = off_offsets + (size_t)(nbuckets + 1) * sizeof(int);
    size_t ws_needed   = off_cursor + (size_t)nbuckets * sizeof(int);

    if (nbuckets > MAX_BUCKETS || ws_size < ws_needed) {
        int threads = 256;
        zero_out<<<(out_size + threads - 1) / threads, threads, 0, stream>>>(out, out_size);
        long long total = (long long)n_edges * N_FEAT;
        mp_scatter_add<<<(int)((total + threads - 1) / threads), threads, 0, stream>>>(
            x, src, dst, out, n_edges);
        return;
    }

    char* ws = (char*)d_ws;
    uint32_t* sorted  = (uint32_t*)(ws + off_sorted);
    int*      hist    = (int*)(ws + off_hist);
    int*      offsets = (int*)(ws + off_offsets);
    int*      cursor  = (int*)(ws + off_cursor);

    hipMemsetAsync(hist, 0, (size_t)nbuckets * sizeof(int), stream);

    hist_kernel<<<256, 256, 0, stream>>>(dst, n_edges, hist, nbuckets);
    scan_kernel<<<1, 1024, 0, stream>>>(hist, nbuckets, offsets, cursor);
    scatter_kernel<<<SCATTER_BLOCKS, 256, 0, stream>>>(src, dst, n_edges, cursor, sorted, nbuckets);
    aggregate_kernel<<<nbuckets, 256, 0, stream>>>(x, sorted, offsets, out, n_nodes);
}

// Round 4
// 231.138 us; speedup vs baseline: 1.8929x; 1.5730x over previous
//
#include <hip/hip_runtime.h>
#include <stdint.h>

#define N_FEAT 32
#define SCAN_T 1024

// ---------- fallback path (baseline, known-correct, 177us) ----------
__global__ void zero_out(float* __restrict__ out, int n) {
    int i = blockIdx.x * blockDim.x + threadIdx.x;
    if (i < n) out[i] = 0.0f;
}

__global__ void mp_scatter_add(const float* __restrict__ x,
                               const int* __restrict__ src,
                               const int* __restrict__ dst,
                               float* __restrict__ out,
                               int n_edges) {
    long long tid = (long long)blockIdx.x * blockDim.x + threadIdx.x;
    long long total = (long long)n_edges * N_FEAT;
    if (tid >= total) return;
    int e = (int)(tid >> 5);
    int f = (int)(tid & 31);
    atomicAdd(&out[(long long)dst[e] * N_FEAT + f],
              x[(long long)src[e] * N_FEAT + f]);
}

// ---------- fast path: full counting-sort by destination NODE ----------
// No atomics and no LDS in the aggregation kernel: each node's edges are
// contiguous after the sort, so a 32-lane group accumulates in registers.

// K1: per-node histogram. 1.6M global int atomics over 100K addresses (~16-way).
__global__ void hist_node(const int* __restrict__ dst, int n_edges,
                          int* __restrict__ hist) {
    int stride = gridDim.x * blockDim.x;
    for (int i = blockIdx.x * blockDim.x + threadIdx.x; i < n_edges; i += stride)
        atomicAdd(&hist[dst[i]], 1);
}

// K2a: per-block inclusive scan of hist chunk -> offsets[idx+1] (local), block sums.
__global__ void scan_local(const int* __restrict__ hist, int n,
                           int* __restrict__ offsets, int* __restrict__ bsum) {
    __shared__ int s[SCAN_T];
    int idx = blockIdx.x * SCAN_T + threadIdx.x;
    int v = (idx < n) ? hist[idx] : 0;
    s[threadIdx.x] = v;
    __syncthreads();
    for (int off = 1; off < SCAN_T; off <<= 1) {
        int t = (threadIdx.x >= off) ? s[threadIdx.x - off] : 0;
        __syncthreads();
        s[threadIdx.x] += t;
        __syncthreads();
    }
    if (idx < n) offsets[idx + 1] = s[threadIdx.x];
    if (threadIdx.x == SCAN_T - 1) bsum[blockIdx.x] = s[SCAN_T - 1];
}

// K2b: single-block exclusive scan of the <=1024 block sums.
__global__ void scan_bsum(const int* __restrict__ bsum, int* __restrict__ bofs,
                          int nb, int* __restrict__ offsets) {
    __shared__ int s[SCAN_T];
    int t = threadIdx.x;
    int v = (t < nb) ? bsum[t] : 0;
    s[t] = v;
    __syncthreads();
    for (int off = 1; off < SCAN_T; off <<= 1) {
        int u = (t >= off) ? s[t - off] : 0;
        __syncthreads();
        s[t] += u;
        __syncthreads();
    }
    if (t < nb) bofs[t] = s[t] - v;          // exclusive
    if (t == 0) offsets[0] = 0;
}

// K2c: add block offsets; derive per-node start cursor.
__global__ void scan_fix(const int* __restrict__ hist, int n,
                         int* __restrict__ offsets, const int* __restrict__ bofs,
                         int* __restrict__ cursor) {
    int idx = blockIdx.x * SCAN_T + threadIdx.x;
    if (idx < n) {
        int incl = offsets[idx + 1] + bofs[blockIdx.x];
        offsets[idx + 1] = incl;
        cursor[idx] = incl - hist[idx];      // exclusive start of node idx
    }
}

// K3: scatter src ids into dst-sorted order.
__global__ void scatter_node(const int* __restrict__ src, const int* __restrict__ dst,
                             int n_edges, int* __restrict__ cursor,
                             uint32_t* __restrict__ sorted) {
    int stride = gridDim.x * blockDim.x;
    for (int i = blockIdx.x * blockDim.x + threadIdx.x; i < n_edges; i += stride) {
        int pos = atomicAdd(&cursor[dst[i]], 1);
        sorted[pos] = (uint32_t)src[i];
    }
}

// K4: one 32-lane group per node. Register accumulation, 8 gathers in flight,
// each output row written exactly once. No LDS, no atomics.
__global__ void __launch_bounds__(256)
aggregate_by_node(const float* __restrict__ x,
                  const uint32_t* __restrict__ sorted,
                  const int* __restrict__ offsets,
                  float* __restrict__ out, int n_nodes) {
    int g = (int)((blockIdx.x * (long long)blockDim.x + threadIdx.x) >> 5); // node id
    int f = threadIdx.x & (N_FEAT - 1);                                     // feature lane
    if (g >= n_nodes) return;
    int beg = offsets[g];
    int end = offsets[g + 1];
    float acc = 0.0f;
    for (int i = beg; i < end; i += 8) {
        uint32_t s[8];
        float v[8];
#pragma unroll
        for (int k = 0; k < 8; ++k) {
            int j = i + k;
            s[k] = (j < end) ? sorted[j] : sorted[i];   // clamp: sorted[i] always valid here
        }
#pragma unroll
        for (int k = 0; k < 8; ++k)
            v[k] = x[(size_t)s[k] * N_FEAT + f];        // 8 independent 128B row gathers
#pragma unroll
        for (int k = 0; k < 8; ++k)
            acc += ((i + k) < end) ? v[k] : 0.0f;
    }
    out[(size_t)g * N_FEAT + f] = acc;
}

extern "C" void kernel_launch(void* const* d_in, const int* in_sizes, int n_in,
                              void* d_out, int out_size, void* d_ws, size_t ws_size,
                              hipStream_t stream) {
    const float* x   = (const float*)d_in[0];
    const int*   ei  = (const int*)d_in[1];
    float*       out = (float*)d_out;

    const int n_edges = in_sizes[1] / 2;
    const int n_nodes = in_sizes[0] / N_FEAT;
    const int* src = ei;
    const int* dst = ei + n_edges;

    const int nscan = (n_nodes + SCAN_T - 1) / SCAN_T;

    // workspace layout
    size_t off_sorted  = 0;
    size_t off_hist    = off_sorted + (size_t)n_edges * sizeof(uint32_t);
    size_t off_offsets = off_hist + (size_t)n_nodes * sizeof(int);
    size_t off_cursor  = off_offsets + (size_t)(n_nodes + 1) * sizeof(int);
    size_t off_bsum    = off_cursor + (size_t)n_nodes * sizeof(int);
    size_t off_bofs    = off_bsum + (size_t)nscan * sizeof(int);
    size_t ws_needed   = off_bofs + (size_t)nscan * sizeof(int);

    if (nscan > SCAN_T || ws_size < ws_needed) {
        // fallback: baseline atomic scatter (correct, ~177us)
        int threads = 256;
        zero_out<<<(out_size + threads - 1) / threads, threads, 0, stream>>>(out, out_size);
        long long total = (long long)n_edges * N_FEAT;
        mp_scatter_add<<<(int)((total + threads - 1) / threads), threads, 0, stream>>>(
            x, src, dst, out, n_edges);
        return;
    }

    char* ws = (char*)d_ws;
    uint32_t* sorted  = (uint32_t*)(ws + off_sorted);
    int*      hist    = (int*)(ws + off_hist);
    int*      offsets = (int*)(ws + off_offsets);
    int*      cursor  = (int*)(ws + off_cursor);
    int*      bsum    = (int*)(ws + off_bsum);
    int*      bofs    = (int*)(ws + off_bofs);

    hipMemsetAsync(hist, 0, (size_t)n_nodes * sizeof(int), stream);

    hist_node<<<2048, 256, 0, stream>>>(dst, n_edges, hist);
    scan_local<<<nscan, SCAN_T, 0, stream>>>(hist, n_nodes, offsets, bsum);
    scan_bsum<<<1, SCAN_T, 0, stream>>>(bsum, bofs, nscan, offsets);
    scan_fix<<<nscan, SCAN_T, 0, stream>>>(hist, n_nodes, offsets, bofs, cursor);
    scatter_node<<<2048, 256, 0, stream>>>(src, dst, n_edges, cursor, sorted);

    int agg_blocks = (n_nodes * (N_FEAT / 1) + 0, (n_nodes + 7) / 8);
    aggregate_by_node<<<(n_nodes + 7) / 8, 256, 0, stream>>>(x, sorted, offsets, out, n_nodes);
    (void)agg_blocks;
}

// Round 5
// 180.063 us; speedup vs baseline: 2.4299x; 1.2837x over previous
//
#include <hip/hip_runtime.h>
#include <stdint.h>

#define N_FEAT 32
#define SCAN_T 1024
#define NXCD 8

// ---------- fallback path (baseline, known-correct, 177us) ----------
__global__ void zero_out(float* __restrict__ out, int n) {
    int i = blockIdx.x * blockDim.x + threadIdx.x;
    if (i < n) out[i] = 0.0f;
}

__global__ void mp_scatter_add(const float* __restrict__ x,
                               const int* __restrict__ src,
                               const int* __restrict__ dst,
                               float* __restrict__ out,
                               int n_edges) {
    long long tid = (long long)blockIdx.x * blockDim.x + threadIdx.x;
    long long total = (long long)n_edges * N_FEAT;
    if (tid >= total) return;
    int e = (int)(tid >> 5);
    int f = (int)(tid & 31);
    atomicAdd(&out[(long long)dst[e] * N_FEAT + f],
              x[(long long)src[e] * N_FEAT + f]);
}

// ---------- fast path: counting-sort by destination node ----------

// K1: per-node histogram.
__global__ void hist_node(const int* __restrict__ dst, int n_edges,
                          int* __restrict__ hist) {
    int stride = gridDim.x * blockDim.x;
    for (int i = blockIdx.x * blockDim.x + threadIdx.x; i < n_edges; i += stride)
        atomicAdd(&hist[dst[i]], 1);
}

// K2a: per-block inclusive scan of hist chunk -> offsets[idx+1] (local), block sums.
__global__ void scan_local(const int* __restrict__ hist, int n,
                           int* __restrict__ offsets, int* __restrict__ bsum) {
    __shared__ int s[SCAN_T];
    int idx = blockIdx.x * SCAN_T + threadIdx.x;
    int v = (idx < n) ? hist[idx] : 0;
    s[threadIdx.x] = v;
    __syncthreads();
    for (int off = 1; off < SCAN_T; off <<= 1) {
        int t = (threadIdx.x >= off) ? s[threadIdx.x - off] : 0;
        __syncthreads();
        s[threadIdx.x] += t;
        __syncthreads();
    }
    if (idx < n) offsets[idx + 1] = s[threadIdx.x];
    if (threadIdx.x == SCAN_T - 1) bsum[blockIdx.x] = s[SCAN_T - 1];
}

// K2b: single-block exclusive scan of the <=1024 block sums.
__global__ void scan_bsum(const int* __restrict__ bsum, int* __restrict__ bofs,
                          int nb, int* __restrict__ offsets) {
    __shared__ int s[SCAN_T];
    int t = threadIdx.x;
    int v = (t < nb) ? bsum[t] : 0;
    s[t] = v;
    __syncthreads();
    for (int off = 1; off < SCAN_T; off <<= 1) {
        int u = (t >= off) ? s[t - off] : 0;
        __syncthreads();
        s[t] += u;
        __syncthreads();
    }
    if (t < nb) bofs[t] = s[t] - v;          // exclusive
    if (t == 0) offsets[0] = 0;
}

// K2c: add block offsets; derive per-node start cursor.
__global__ void scan_fix(const int* __restrict__ hist, int n,
                         int* __restrict__ offsets, const int* __restrict__ bofs,
                         int* __restrict__ cursor) {
    int idx = blockIdx.x * SCAN_T + threadIdx.x;
    if (idx < n) {
        int incl = offsets[idx + 1] + bofs[blockIdx.x];
        offsets[idx + 1] = incl;
        cursor[idx] = incl - hist[idx];      // exclusive start of node idx
    }
}

// K3: XCD-cohort scatter. Blocks form 8 cohorts via blockIdx&7 (default
// round-robin blockIdx->XCD). Cohort c processes ONLY edges with dst in node
// range c, so every 64B line of `sorted` is written from a single XCD's L2:
// stores merge in L2 and each line goes to HBM once (kills the 16x
// write-through amplification seen when random XCDs shared lines).
// Correctness does not depend on the XCD mapping: the 8 cohorts partition
// edges by dst-range, each edge written exactly once.
__global__ void scatter_xcd(const int* __restrict__ src, const int* __restrict__ dst,
                            int n_edges, int n_nodes,
                            int* __restrict__ cursor, uint32_t* __restrict__ sorted) {
    const int xcd = blockIdx.x & (NXCD - 1);
    const int cb  = blockIdx.x >> 3;                 // block index within cohort
    const int CB  = gridDim.x >> 3;                  // blocks per cohort
    const int rng = (n_nodes + NXCD - 1) / NXCD;
    const int rlo = xcd * rng;
    const int rhi = min(rlo + rng, n_nodes);
    const int stride = CB * blockDim.x;
    for (int i = cb * blockDim.x + threadIdx.x; i < n_edges; i += stride) {
        int d = dst[i];
        if (d >= rlo && d < rhi) {
            int pos = atomicAdd(&cursor[d], 1);
            sorted[pos] = (uint32_t)src[i];
        }
    }
}

// K4: one 32-lane group per node. Register accumulation, 8 gathers in flight,
// each output row written exactly once. No LDS, no atomics.
__global__ void __launch_bounds__(256)
aggregate_by_node(const float* __restrict__ x,
                  const uint32_t* __restrict__ sorted,
                  const int* __restrict__ offsets,
                  float* __restrict__ out, int n_nodes) {
    int g = (int)((blockIdx.x * (long long)blockDim.x + threadIdx.x) >> 5); // node id
    int f = threadIdx.x & (N_FEAT - 1);                                     // feature lane
    if (g >= n_nodes) return;
    int beg = offsets[g];
    int end = offsets[g + 1];
    float acc = 0.0f;
    for (int i = beg; i < end; i += 8) {
        uint32_t s[8];
        float v[8];
#pragma unroll
        for (int k = 0; k < 8; ++k) {
            int j = i + k;
            s[k] = (j < end) ? sorted[j] : sorted[i];   // clamp: sorted[i] always valid here
        }
#pragma unroll
        for (int k = 0; k < 8; ++k)
            v[k] = x[(size_t)s[k] * N_FEAT + f];        // 8 independent 128B row gathers
#pragma unroll
        for (int k = 0; k < 8; ++k)
            acc += ((i + k) < end) ? v[k] : 0.0f;
    }
    out[(size_t)g * N_FEAT + f] = acc;
}

extern "C" void kernel_launch(void* const* d_in, const int* in_sizes, int n_in,
                              void* d_out, int out_size, void* d_ws, size_t ws_size,
                              hipStream_t stream) {
    const float* x   = (const float*)d_in[0];
    const int*   ei  = (const int*)d_in[1];
    float*       out = (float*)d_out;

    const int n_edges = in_sizes[1] / 2;
    const int n_nodes = in_sizes[0] / N_FEAT;
    const int* src = ei;
    const int* dst = ei + n_edges;

    const int nscan = (n_nodes + SCAN_T - 1) / SCAN_T;

    // workspace layout
    size_t off_sorted  = 0;
    size_t off_hist    = off_sorted + (size_t)n_edges * sizeof(uint32_t);
    size_t off_offsets = off_hist + (size_t)n_nodes * sizeof(int);
    size_t off_cursor  = off_offsets + (size_t)(n_nodes + 1) * sizeof(int);
    size_t off_bsum    = off_cursor + (size_t)n_nodes * sizeof(int);
    size_t off_bofs    = off_bsum + (size_t)nscan * sizeof(int);
    size_t ws_needed   = off_bofs + (size_t)nscan * sizeof(int);

    if (nscan > SCAN_T || ws_size < ws_needed) {
        // fallback: baseline atomic scatter (correct, ~177us)
        int threads = 256;
        zero_out<<<(out_size + threads - 1) / threads, threads, 0, stream>>>(out, out_size);
        long long total = (long long)n_edges * N_FEAT;
        mp_scatter_add<<<(int)((total + threads - 1) / threads), threads, 0, stream>>>(
            x, src, dst, out, n_edges);
        return;
    }

    char* ws = (char*)d_ws;
    uint32_t* sorted  = (uint32_t*)(ws + off_sorted);
    int*      hist    = (int*)(ws + off_hist);
    int*      offsets = (int*)(ws + off_offsets);
    int*      cursor  = (int*)(ws + off_cursor);
    int*      bsum    = (int*)(ws + off_bsum);
    int*      bofs    = (int*)(ws + off_bofs);

    hipMemsetAsync(hist, 0, (size_t)n_nodes * sizeof(int), stream);

    hist_node<<<2048, 256, 0, stream>>>(dst, n_edges, hist);
    scan_local<<<nscan, SCAN_T, 0, stream>>>(hist, n_nodes, offsets, bsum);
    scan_bsum<<<1, SCAN_T, 0, stream>>>(bsum, bofs, nscan, offsets);
    scan_fix<<<nscan, SCAN_T, 0, stream>>>(hist, n_nodes, offsets, bofs, cursor);
    scatter_xcd<<<2048, 256, 0, stream>>>(src, dst, n_edges, n_nodes, cursor, sorted);
    aggregate_by_node<<<(n_nodes + 7) / 8, 256, 0, stream>>>(x, sorted, offsets, out, n_nodes);
}